// Round 5
// baseline (880.961 us; speedup 1.0000x reference)
//
#include <hip/hip_runtime.h>
#include <hip/hip_bf16.h>
#include <math.h>

#define NTOK 16384
#define HDIM 1024
#define DSZ 32
#define DGZ 32
#define FMZ 64
#define NEXP 4
#define FFZ 2048

typedef __attribute__((ext_vector_type(4))) float f32x4;
typedef __attribute__((ext_vector_type(16))) float f32x16;
typedef __attribute__((ext_vector_type(8))) short bf16x8;

__device__ __forceinline__ unsigned short f2bf(float f){
    union { float f; unsigned int u; } v; v.f = f;
    unsigned int r = (v.u + 0x7FFFu + ((v.u >> 16) & 1u)) >> 16;
    return (unsigned short)r;
}
__device__ __forceinline__ float gelu_f(float x){
    return 0.5f * x * (1.0f + erff(x * 0.70710678118654752440f));
}
__device__ __forceinline__ void gld_lds16(const void* g, void* s){
    __builtin_amdgcn_global_load_lds((const __attribute__((address_space(1))) unsigned int*)g,
                                     (__attribute__((address_space(3))) unsigned int*)s, 16, 0, 0);
}

// ---------------- kernel 1: per-token LN stats + h -> bf16 ----------------
__global__ __launch_bounds__(256) void k_stats(const float* __restrict__ h,
        unsigned short* __restrict__ hbf, float* __restrict__ mu_g, float* __restrict__ rs_g){
    int tid = threadIdx.x;
    int wv = tid >> 6, l = tid & 63;
    int tok = blockIdx.x * 4 + wv;
    const float4* hp = (const float4*)(h + (size_t)tok * HDIM);
    ushort4* op = (ushort4*)(hbf + (size_t)tok * HDIM);
    float s = 0.f, s2 = 0.f;
    #pragma unroll
    for (int p = 0; p < 4; ++p){
        float4 v = hp[p * 64 + l];
        s  += v.x + v.y + v.z + v.w;
        s2 += v.x*v.x + v.y*v.y + v.z*v.z + v.w*v.w;
        ushort4 o; o.x = f2bf(v.x); o.y = f2bf(v.y); o.z = f2bf(v.z); o.w = f2bf(v.w);
        op[p * 64 + l] = o;
    }
    #pragma unroll
    for (int off = 32; off >= 1; off >>= 1){
        s  += __shfl_xor(s,  off, 64);
        s2 += __shfl_xor(s2, off, 64);
    }
    if (l == 0){
        float mu = s * (1.0f / HDIM);
        float var = s2 * (1.0f / HDIM) - mu * mu;
        var = fmaxf(var, 0.f);
        mu_g[tok] = mu;
        rs_g[tok] = 1.0f / sqrtf(var + 1e-5f);
    }
}

// ---------------- kernel 2: transpose + fp32->bf16 (weights, per expert) ----------------
__global__ __launch_bounds__(256) void k_transpose_bf(const float* __restrict__ in,
        unsigned short* __restrict__ out, int R, int C){
    __shared__ float tile[32][33];
    size_t mat = (size_t)blockIdx.z * R * C;
    int bx = blockIdx.x * 32;   // col base
    int by = blockIdx.y * 32;   // row base
    int x = threadIdx.x, y = threadIdx.y;
    const float* ip = in + mat;
    unsigned short* op = out + mat;
    #pragma unroll
    for (int i = 0; i < 32; i += 8)
        tile[y + i][x] = ip[(size_t)(by + y + i) * C + (bx + x)];
    __syncthreads();
    #pragma unroll
    for (int i = 0; i < 32; i += 8)
        op[(size_t)(bx + y + i) * R + (by + x)] = f2bf(tile[x][y + i]);
}

// ---------------- kernel 3: fused fp32 routing (unchanged, verified) ----------------
__global__ __launch_bounds__(256) void k_route(
    const float* __restrict__ h, const float* __restrict__ tok_emb,
    const float* __restrict__ ln_g, const float* __restrict__ ln_b,
    const float* __restrict__ Wg, const float* __restrict__ bg,
    const float* __restrict__ Wf, const float* __restrict__ bfv,
    const float* __restrict__ Wr, const float* __restrict__ br,
    const float* __restrict__ mu_g, const float* __restrict__ rs_g,
    float* __restrict__ tprob, int* __restrict__ list, int* __restrict__ cnt,
    float* __restrict__ imp_part)
{
    __shared__ __align__(16) char smem[62208];
    float* lgs  = (float*)(smem);                      // [1024]
    float* lbs  = (float*)(smem + 4096);               // [1024]
    float (*hsT)[64]  = (float(*)[64])(smem + 8192);   // [64 k][64 tok]
    float (*wgs)[32]  = (float(*)[32])(smem + 24576);  // [64 k][32 c]
    float (*gacc)[32] = (float(*)[32])(smem + 32768);  // [64 tok][32 c]
    float* mus = (float*)(smem + 40960);               // [64]
    float* rss = (float*)(smem + 41216);               // [64]
    float (*wrs)[4]     = (float(*)[4])(smem + 41472); // [64][4]
    float (*logit_s)[5] = (float(*)[5])(smem + 42496);
    float (*prob_s)[5]  = (float(*)[5])(smem + 43776);
    int* lcnt  = (int*)(smem + 45056);
    int* lbase = (int*)(smem + 45072);
    float (*agT)[64] = (float(*)[64])(smem);           // [64 j][64 tok]
    float (*wfs)[64] = (float(*)[64])(smem + 16384);   // [64 k][64 f]
    float (*uT)[64]  = (float(*)[64])(smem + 45824);   // [64 f][64 tok]

    int tid = threadIdx.x;
    int t0 = blockIdx.x * 64;

    ((float4*)lgs)[tid] = ((const float4*)ln_g)[tid];
    ((float4*)lbs)[tid] = ((const float4*)ln_b)[tid];
    if (tid < 64){ mus[tid] = mu_g[t0 + tid]; rss[tid] = rs_g[t0 + tid]; }
    if (tid < 64) ((float4*)wrs)[tid] = ((const float4*)Wr)[tid];
    if (tid < 4) lcnt[tid] = 0;
    __syncthreads();

    int l = tid & 63, w = tid >> 6;
    int tg = l & 7, cg = l >> 3, q = w;
    float g_[8][4];
    #pragma unroll
    for (int i=0;i<8;++i){ g_[i][0]=0.f; g_[i][1]=0.f; g_[i][2]=0.f; g_[i][3]=0.f; }
    int tokrow = tid >> 2;
    float m_ = mus[tokrow], r_ = rss[tokrow];
    const float* hrow = h + (size_t)(t0 + tokrow) * HDIM;

    for (int k0 = 0; k0 < HDIM; k0 += 64){
        #pragma unroll
        for (int p = 0; p < 4; ++p){
            int f4 = (tid & 3) + 4 * p;
            float4 v = ((const float4*)(hrow + k0))[f4];
            int c = f4 * 4;
            hsT[c+0][tokrow] = (v.x - m_) * r_ * lgs[k0+c+0] + lbs[k0+c+0];
            hsT[c+1][tokrow] = (v.y - m_) * r_ * lgs[k0+c+1] + lbs[k0+c+1];
            hsT[c+2][tokrow] = (v.z - m_) * r_ * lgs[k0+c+2] + lbs[k0+c+2];
            hsT[c+3][tokrow] = (v.w - m_) * r_ * lgs[k0+c+3] + lbs[k0+c+3];
        }
        {
            int wgrow = tid >> 2;
            #pragma unroll
            for (int p = 0; p < 2; ++p){
                int f4 = (tid & 3) + 4 * p;
                ((float4*)wgs[wgrow])[f4] = ((const float4*)(Wg + (size_t)(k0 + wgrow) * DGZ))[f4];
            }
        }
        __syncthreads();
        #pragma unroll
        for (int kk16 = 0; kk16 < 16; ++kk16){
            int kk = q * 16 + kk16;
            float4 a0 = ((float4*)hsT[kk])[tg*2];
            float4 a1 = ((float4*)hsT[kk])[tg*2+1];
            float4 wv = ((float4*)wgs[kk])[cg];
            float av[8] = {a0.x,a0.y,a0.z,a0.w,a1.x,a1.y,a1.z,a1.w};
            float wj[4] = {wv.x,wv.y,wv.z,wv.w};
            #pragma unroll
            for (int i=0;i<8;++i){
                g_[i][0] += av[i]*wj[0]; g_[i][1] += av[i]*wj[1];
                g_[i][2] += av[i]*wj[2]; g_[i][3] += av[i]*wj[3];
            }
        }
        __syncthreads();
    }
    for (int qq = 0; qq < 4; ++qq){
        if (w == qq){
            #pragma unroll
            for (int i=0;i<8;++i){
                int tok = tg*8+i;
                #pragma unroll
                for (int j=0;j<4;++j){
                    int c = cg*4+j;
                    if (qq == 0) gacc[tok][c] = g_[i][j];
                    else gacc[tok][c] += g_[i][j];
                }
            }
        }
        __syncthreads();
    }
    {
        int tokr = tid >> 2;
        #pragma unroll
        for (int p = 0; p < 2; ++p){
            int f4 = (tid & 3) + 4*p;
            float4 v = ((const float4*)(tok_emb + (size_t)(t0 + tokr) * DSZ))[f4];
            int j = f4 * 4;
            agT[j+0][tokr] = v.x; agT[j+1][tokr] = v.y;
            agT[j+2][tokr] = v.z; agT[j+3][tokr] = v.w;
        }
        int c = tid & 31, tok8 = (tid >> 5) * 8;
        float bgc = bg[c];
        #pragma unroll
        for (int i=0;i<8;++i){
            int tok = tok8 + i;
            agT[32 + c][tok] = gelu_f(gacc[tok][c] + bgc);
        }
        int row = tid >> 2;
        #pragma unroll
        for (int p = 0; p < 4; ++p){
            int f4 = (tid & 3) + 4*p;
            ((float4*)wfs[row])[f4] = ((const float4*)(Wf + (size_t)row * FMZ))[f4];
        }
    }
    __syncthreads();
    {
        int tok = tid & 63, fq = tid >> 6;
        float u_[16];
        #pragma unroll
        for (int i=0;i<16;++i) u_[i]=0.f;
        for (int j = 0; j < 64; ++j){
            float a = agT[j][tok];
            float wv[16];
            *(float4*)&wv[0]  = ((float4*)wfs[j])[fq*4+0];
            *(float4*)&wv[4]  = ((float4*)wfs[j])[fq*4+1];
            *(float4*)&wv[8]  = ((float4*)wfs[j])[fq*4+2];
            *(float4*)&wv[12] = ((float4*)wfs[j])[fq*4+3];
            #pragma unroll
            for (int i=0;i<16;++i) u_[i] += a * wv[i];
        }
        #pragma unroll
        for (int i=0;i<16;++i){
            int f = fq*16+i;
            uT[f][tok] = gelu_f(u_[i] + bfv[f]);
        }
    }
    __syncthreads();
    {
        int tok = tid & 63, e = tid >> 6;
        float lt = 0.f;
        #pragma unroll 8
        for (int f = 0; f < 64; ++f) lt += uT[f][tok] * wrs[f][e];
        logit_s[tok][e] = lt + br[e];
    }
    __syncthreads();
    int my_e = 0, my_pos = 0;
    if (tid < 64){
        int tok = tid;
        float l0 = logit_s[tok][0], l1 = logit_s[tok][1];
        float l2 = logit_s[tok][2], l3 = logit_s[tok][3];
        float mx = fmaxf(fmaxf(l0,l1), fmaxf(l2,l3));
        float p0 = expf(l0-mx), p1 = expf(l1-mx), p2 = expf(l2-mx), p3 = expf(l3-mx);
        float inv = 1.0f / (p0+p1+p2+p3);
        int be = 0; float bp = p0;
        if (p1 > bp){ bp = p1; be = 1; }
        if (p2 > bp){ bp = p2; be = 2; }
        if (p3 > bp){ bp = p3; be = 3; }
        tprob[t0 + tok] = bp * inv;
        prob_s[tok][0] = p0*inv; prob_s[tok][1] = p1*inv;
        prob_s[tok][2] = p2*inv; prob_s[tok][3] = p3*inv;
        my_e = be;
        my_pos = atomicAdd(&lcnt[be], 1);
    }
    __syncthreads();
    if (tid < 4) lbase[tid] = atomicAdd(&cnt[tid], lcnt[tid]);
    __syncthreads();
    if (tid < 64) list[my_e * NTOK + lbase[my_e] + my_pos] = t0 + tid;
    if (tid < 4){
        float s = 0.f;
        for (int t = 0; t < 64; ++t) s += prob_s[t][tid];
        imp_part[blockIdx.x * 4 + tid] = s;
    }
}

// ---------------- grouped expert GEMM v3: 128x128 tile, dbuf 2-phase, 32x32x16 ----------------
// 256 threads = 4 waves (2M x 2N); per-wave output 64x64 = 2x2 frags of 32x32.
// LDS 64 KiB (dbuf A 2x16KB + B 2x16KB) -> 2 blocks/CU (inter-block overlap, m114).
// Minimum-2-phase (T3 recipe): STAGE(t+1) issued FIRST, then frag reads(t)+MFMA,
// then one vmcnt(0)+barrier per K-tile (loads issued ~600cy before the wait).
// Swizzle (T2): stored chunk s of row r holds global chunk s ^ (r&7); write side
// pre-swizzles the GLOBAL source (gld_lds dest linear), read side XORs chunk.
// XCD swizzle (T1, bijective): consecutive logical tiles -> same XCD (A-panel L2 reuse).
template<int KTD, int NT, bool PH1>
__global__ __launch_bounds__(256, 2) void k_gemm(
    const unsigned short* __restrict__ Abase,
    const unsigned short* __restrict__ Bbase,
    const int* __restrict__ list, const int* __restrict__ cnt_g,
    const float* __restrict__ bias,
    unsigned short* __restrict__ A1out,
    const float* __restrict__ hres,
    const float* __restrict__ tprob,
    float* __restrict__ outp)
{
    constexpr int NKT = KTD / 64;
    constexpr int GX  = NT / 128;             // 16 (PH1) or 8 (PH2), pow2
    constexpr int NWG = GX * (NTOK / 128);    // 2048 / 1024, %8 == 0
    __shared__ __align__(16) char lds[65536];
    char* ldsB = lds + 32768;

    int e = blockIdx.z;
    int cnt = cnt_g[e];
    // T1: physical (bx,by) -> logical tile fs; XCD k gets logical [k*NWG/8, (k+1)*NWG/8)
    int f  = blockIdx.y * GX + blockIdx.x;
    int fs = (f & 7) * (NWG >> 3) + (f >> 3);
    int m0 = (fs / GX) * 128;
    int n0 = (fs & (GX - 1)) * 128;
    if (m0 >= cnt) return;

    int tid = threadIdx.x, w = tid >> 6, l = tid & 63;
    int wr = w >> 1, wc = w & 1;
    const int* lrow = list + e * NTOK;

    // staging: gld i covers rows 32i+(tid>>3), src chunk (tid&7)^((tid>>3)&7); dest = base+4096i+tid*16
    int srow = tid >> 3;
    int jsrc = ((tid & 7) ^ (srow & 7)) * 8;   // element offset of pre-swizzled 16B chunk
    const unsigned short* asrc[4];
    const unsigned short* bsrc[4];
    #pragma unroll
    for (int i = 0; i < 4; ++i){
        int g = m0 + 32 * i + srow; if (g > cnt - 1) g = cnt - 1;
        asrc[i] = Abase + (size_t)lrow[g] * KTD + jsrc;
        bsrc[i] = Bbase + ((size_t)e * NT + n0 + 32 * i + srow) * KTD + jsrc;
    }

    // fragment read offsets: row = l&31 (+wave/frag base), k-chunk = 2*kk + (l>>5), XOR (l&7)
    int arow_off = (wr * 64 + (l & 31)) * 128;
    int brow_off = (wc * 64 + (l & 31)) * 128;
    int khi = l >> 5, cx = l & 7;
    int scw[4];
    #pragma unroll
    for (int kk = 0; kk < 4; ++kk) scw[kk] = ((2 * kk + khi) ^ cx) * 16;

#define STAGE8(KT) do { \
    size_t ko_ = (size_t)(KT) * 64; \
    int nxt_ = ((KT) & 1) * 16384; \
    gld_lds16(asrc[0] + ko_, lds  + nxt_ + tid * 16); \
    gld_lds16(asrc[1] + ko_, lds  + nxt_ + 4096  + tid * 16); \
    gld_lds16(asrc[2] + ko_, lds  + nxt_ + 8192  + tid * 16); \
    gld_lds16(asrc[3] + ko_, lds  + nxt_ + 12288 + tid * 16); \
    gld_lds16(bsrc[0] + ko_, ldsB + nxt_ + tid * 16); \
    gld_lds16(bsrc[1] + ko_, ldsB + nxt_ + 4096  + tid * 16); \
    gld_lds16(bsrc[2] + ko_, ldsB + nxt_ + 8192  + tid * 16); \
    gld_lds16(bsrc[3] + ko_, ldsB + nxt_ + 12288 + tid * 16); } while(0)
#define AF(CUR, MF, KK) (*(const bf16x8*)(lds  + (CUR) + (MF) * 4096 + arow_off + scw[KK]))
#define BF(CUR, NF, KK) (*(const bf16x8*)(ldsB + (CUR) + (NF) * 4096 + brow_off + scw[KK]))
#define KSTEP(KT, CUR) do { \
    if ((KT) + 1 < NKT) STAGE8((KT) + 1); \
    bf16x8 a0_[4], a1_[4], b0_[4], b1_[4]; \
    _Pragma("unroll") \
    for (int kk = 0; kk < 4; ++kk){ \
        a0_[kk] = AF(CUR, 0, kk); a1_[kk] = AF(CUR, 1, kk); \
        b0_[kk] = BF(CUR, 0, kk); b1_[kk] = BF(CUR, 1, kk); } \
    __builtin_amdgcn_s_setprio(1); \
    _Pragma("unroll") \
    for (int kk = 0; kk < 4; ++kk){ \
        acc00 = __builtin_amdgcn_mfma_f32_32x32x16_bf16(a0_[kk], b0_[kk], acc00, 0, 0, 0); \
        acc01 = __builtin_amdgcn_mfma_f32_32x32x16_bf16(a0_[kk], b1_[kk], acc01, 0, 0, 0); \
        acc10 = __builtin_amdgcn_mfma_f32_32x32x16_bf16(a1_[kk], b0_[kk], acc10, 0, 0, 0); \
        acc11 = __builtin_amdgcn_mfma_f32_32x32x16_bf16(a1_[kk], b1_[kk], acc11, 0, 0, 0); } \
    __builtin_amdgcn_s_setprio(0); \
    asm volatile("s_waitcnt vmcnt(0)" ::: "memory"); \
    __builtin_amdgcn_s_barrier(); } while(0)

    f32x16 acc00 = {}, acc01 = {}, acc10 = {}, acc11 = {};

    STAGE8(0);
    asm volatile("s_waitcnt vmcnt(0)" ::: "memory");
    __builtin_amdgcn_s_barrier();

    #pragma unroll 1
    for (int kt = 0; kt < NKT; kt += 2){
        KSTEP(kt,     0);
        KSTEP(kt + 1, 16384);
    }

    // epilogue: 32x32 C/D layout: col = l&31, row = (reg&3) + 8*(reg>>2) + 4*(l>>5)
    float bs[2];
    bs[0] = bias[e * NT + n0 + wc * 64 +      (l & 31)];
    bs[1] = bias[e * NT + n0 + wc * 64 + 32 + (l & 31)];
    #pragma unroll
    for (int mf = 0; mf < 2; ++mf){
        #pragma unroll
        for (int reg = 0; reg < 16; ++reg){
            int row = wr * 64 + mf * 32 + (reg & 3) + 8 * (reg >> 2) + 4 * (l >> 5);
            int g = m0 + row;
            if (g < cnt){
                int tok = lrow[g];
                float v0 = (mf ? acc10[reg] : acc00[reg]) + bs[0];
                float v1 = (mf ? acc11[reg] : acc01[reg]) + bs[1];
                if (PH1){
                    unsigned short* orow = A1out + (size_t)tok * FFZ + n0 + wc * 64 + (l & 31);
                    orow[0]  = f2bf(gelu_f(v0));
                    orow[32] = f2bf(gelu_f(v1));
                } else {
                    float sc = 0.5f * tprob[tok];
                    size_t o = (size_t)tok * HDIM + n0 + wc * 64 + (l & 31);
                    outp[o]      = hres[o]      + sc * v0;
                    outp[o + 32] = hres[o + 32] + sc * v1;
                }
            }
        }
    }
#undef STAGE8
#undef AF
#undef BF
#undef KSTEP
}

// ---------------- final: lb_loss ----------------
__global__ void k_final(const float* __restrict__ imp_part, const int* __restrict__ cnt,
                        float* __restrict__ outp){
    __shared__ float imp_s[4];
    int tid = threadIdx.x;
    if (tid < 4){
        float s = 0.f;
        for (int b = 0; b < 256; ++b) s += imp_part[b*4 + tid];
        imp_s[tid] = s;
    }
    __syncthreads();
    if (tid == 0){
        float lb = 0.f;
        #pragma unroll
        for (int e = 0; e < 4; ++e) lb += imp_s[e] * (float)cnt[e];
        outp[(size_t)NTOK * HDIM] = (float)NEXP * lb / ((float)NTOK * (float)NTOK + 1e-8f);
    }
}

extern "C" void kernel_launch(void* const* d_in, const int* in_sizes, int n_in,
                              void* d_out, int out_size, void* d_ws, size_t ws_size,
                              hipStream_t stream){
    const float* h       = (const float*)d_in[0];
    const float* tok_emb = (const float*)d_in[1];
    const float* ln_g = (const float*)d_in[3];
    const float* ln_b = (const float*)d_in[4];
    const float* Wg   = (const float*)d_in[5];
    const float* bg   = (const float*)d_in[6];
    const float* Wf   = (const float*)d_in[7];
    const float* bfv  = (const float*)d_in[8];
    const float* Wr   = (const float*)d_in[9];
    const float* br   = (const float*)d_in[10];
    const float* W1   = (const float*)d_in[11];
    const float* b1   = (const float*)d_in[12];
    const float* W2   = (const float*)d_in[13];
    const float* b2   = (const float*)d_in[14];
    float* outp = (float*)d_out;
    char* ws = (char*)d_ws;

    unsigned short* h_bf = (unsigned short*)(ws);               // 33554432 B
    unsigned short* W1T  = (unsigned short*)(ws + 33554432);    // 16777216 B  [E][FFZ][HDIM]
    unsigned short* W2T  = (unsigned short*)(ws + 50331648);    // 16777216 B  [E][HDIM][FFZ]
    unsigned short* A1   = (unsigned short*)(ws + 67108864);    // 67108864 B  [NTOK][FFZ]
    float* mu_g  = (float*)(ws + 134217728);
    float* rs_g  = (float*)(ws + 134283264);
    float* tprob = (float*)(ws + 134348800);
    int*   list  = (int*)(ws + 134414336);                      // [E][NTOK]
    int*   cnt   = (int*)(ws + 134676480);                      // [E]
    float* imp   = (float*)(ws + 134676736);                    // [256][E]

    hipMemsetAsync(cnt, 0, NEXP * sizeof(int), stream);
    k_stats<<<NTOK/4, 256, 0, stream>>>(h, h_bf, mu_g, rs_g);
    k_transpose_bf<<<dim3(FFZ/32, HDIM/32, NEXP), dim3(32,8), 0, stream>>>(W1, W1T, HDIM, FFZ);
    k_transpose_bf<<<dim3(HDIM/32, FFZ/32, NEXP), dim3(32,8), 0, stream>>>(W2, W2T, FFZ, HDIM);
    k_route<<<NTOK/64, 256, 0, stream>>>(h, tok_emb, ln_g, ln_b, Wg, bg, Wf, bfv, Wr, br,
                                         mu_g, rs_g, tprob, list, cnt, imp);
    k_gemm<HDIM, FFZ, true><<<dim3(FFZ/128, NTOK/128, NEXP), 256, 0, stream>>>(
        h_bf, W1T, list, cnt, b1, A1, nullptr, nullptr, nullptr);
    k_gemm<FFZ, HDIM, false><<<dim3(HDIM/128, NTOK/128, NEXP), 256, 0, stream>>>(
        A1, W2T, list, cnt, b2, nullptr, h, tprob, outp);
    k_final<<<1, 64, 0, stream>>>(imp, cnt, outp);
}

// Round 6
// 392.527 us; speedup vs baseline: 2.2443x; 2.2443x over previous
//
#include <hip/hip_runtime.h>
#include <hip/hip_bf16.h>
#include <math.h>

#define NTOK 16384
#define HDIM 1024
#define DSZ 32
#define DGZ 32
#define FMZ 64
#define NEXP 4
#define FFZ 2048

typedef __attribute__((ext_vector_type(4))) float f32x4;
typedef __attribute__((ext_vector_type(8))) short bf16x8;

__device__ __forceinline__ unsigned short f2bf(float f){
    union { float f; unsigned int u; } v; v.f = f;
    unsigned int r = (v.u + 0x7FFFu + ((v.u >> 16) & 1u)) >> 16;
    return (unsigned short)r;
}
__device__ __forceinline__ float gelu_f(float x){
    return 0.5f * x * (1.0f + erff(x * 0.70710678118654752440f));
}
__device__ __forceinline__ void gld_lds16(const void* g, void* s){
    __builtin_amdgcn_global_load_lds((const __attribute__((address_space(1))) unsigned int*)g,
                                     (__attribute__((address_space(3))) unsigned int*)s, 16, 0, 0);
}

// ---------------- kernel 1: per-token LN stats only ----------------
__global__ __launch_bounds__(256) void k_stats(const float* __restrict__ h,
        float* __restrict__ mu_g, float* __restrict__ rs_g){
    int tid = threadIdx.x;
    int wv = tid >> 6, l = tid & 63;
    int tok = blockIdx.x * 4 + wv;
    const float4* hp = (const float4*)(h + (size_t)tok * HDIM);
    float s = 0.f, s2 = 0.f;
    #pragma unroll
    for (int p = 0; p < 4; ++p){
        float4 v = hp[p * 64 + l];
        s  += v.x + v.y + v.z + v.w;
        s2 += v.x*v.x + v.y*v.y + v.z*v.z + v.w*v.w;
    }
    #pragma unroll
    for (int off = 32; off >= 1; off >>= 1){
        s  += __shfl_xor(s,  off, 64);
        s2 += __shfl_xor(s2, off, 64);
    }
    if (l == 0){
        float mu = s * (1.0f / HDIM);
        float var = s2 * (1.0f / HDIM) - mu * mu;
        var = fmaxf(var, 0.f);
        mu_g[tok] = mu;
        rs_g[tok] = 1.0f / sqrtf(var + 1e-5f);
    }
}

// ---------------- kernel 2: transpose + fp32->bf16 (weights, per expert) ----------------
__global__ __launch_bounds__(256) void k_transpose_bf(const float* __restrict__ in,
        unsigned short* __restrict__ out, int R, int C){
    __shared__ float tile[32][33];
    size_t mat = (size_t)blockIdx.z * R * C;
    int bx = blockIdx.x * 32;   // col base
    int by = blockIdx.y * 32;   // row base
    int x = threadIdx.x, y = threadIdx.y;
    const float* ip = in + mat;
    unsigned short* op = out + mat;
    #pragma unroll
    for (int i = 0; i < 32; i += 8)
        tile[y + i][x] = ip[(size_t)(by + y + i) * C + (bx + x)];
    __syncthreads();
    #pragma unroll
    for (int i = 0; i < 32; i += 8)
        op[(size_t)(bx + y + i) * R + (by + x)] = f2bf(tile[x][y + i]);
}

// ---------------- kernel 3: fused fp32 routing (unchanged, verified) ----------------
__global__ __launch_bounds__(256) void k_route(
    const float* __restrict__ h, const float* __restrict__ tok_emb,
    const float* __restrict__ ln_g, const float* __restrict__ ln_b,
    const float* __restrict__ Wg, const float* __restrict__ bg,
    const float* __restrict__ Wf, const float* __restrict__ bfv,
    const float* __restrict__ Wr, const float* __restrict__ br,
    const float* __restrict__ mu_g, const float* __restrict__ rs_g,
    float* __restrict__ tprob, int* __restrict__ list, int* __restrict__ cnt,
    float* __restrict__ imp_part)
{
    __shared__ __align__(16) char smem[62208];
    float* lgs  = (float*)(smem);                      // [1024]
    float* lbs  = (float*)(smem + 4096);               // [1024]
    float (*hsT)[64]  = (float(*)[64])(smem + 8192);   // [64 k][64 tok]
    float (*wgs)[32]  = (float(*)[32])(smem + 24576);  // [64 k][32 c]
    float (*gacc)[32] = (float(*)[32])(smem + 32768);  // [64 tok][32 c]
    float* mus = (float*)(smem + 40960);               // [64]
    float* rss = (float*)(smem + 41216);               // [64]
    float (*wrs)[4]     = (float(*)[4])(smem + 41472); // [64][4]
    float (*logit_s)[5] = (float(*)[5])(smem + 42496);
    float (*prob_s)[5]  = (float(*)[5])(smem + 43776);
    int* lcnt  = (int*)(smem + 45056);
    int* lbase = (int*)(smem + 45072);
    float (*agT)[64] = (float(*)[64])(smem);           // [64 j][64 tok]
    float (*wfs)[64] = (float(*)[64])(smem + 16384);   // [64 k][64 f]
    float (*uT)[64]  = (float(*)[64])(smem + 45824);   // [64 f][64 tok]

    int tid = threadIdx.x;
    int t0 = blockIdx.x * 64;

    ((float4*)lgs)[tid] = ((const float4*)ln_g)[tid];
    ((float4*)lbs)[tid] = ((const float4*)ln_b)[tid];
    if (tid < 64){ mus[tid] = mu_g[t0 + tid]; rss[tid] = rs_g[t0 + tid]; }
    if (tid < 64) ((float4*)wrs)[tid] = ((const float4*)Wr)[tid];
    if (tid < 4) lcnt[tid] = 0;
    __syncthreads();

    int l = tid & 63, w = tid >> 6;
    int tg = l & 7, cg = l >> 3, q = w;
    float g_[8][4];
    #pragma unroll
    for (int i=0;i<8;++i){ g_[i][0]=0.f; g_[i][1]=0.f; g_[i][2]=0.f; g_[i][3]=0.f; }
    int tokrow = tid >> 2;
    float m_ = mus[tokrow], r_ = rss[tokrow];
    const float* hrow = h + (size_t)(t0 + tokrow) * HDIM;

    for (int k0 = 0; k0 < HDIM; k0 += 64){
        #pragma unroll
        for (int p = 0; p < 4; ++p){
            int f4 = (tid & 3) + 4 * p;
            float4 v = ((const float4*)(hrow + k0))[f4];
            int c = f4 * 4;
            hsT[c+0][tokrow] = (v.x - m_) * r_ * lgs[k0+c+0] + lbs[k0+c+0];
            hsT[c+1][tokrow] = (v.y - m_) * r_ * lgs[k0+c+1] + lbs[k0+c+1];
            hsT[c+2][tokrow] = (v.z - m_) * r_ * lgs[k0+c+2] + lbs[k0+c+2];
            hsT[c+3][tokrow] = (v.w - m_) * r_ * lgs[k0+c+3] + lbs[k0+c+3];
        }
        {
            int wgrow = tid >> 2;
            #pragma unroll
            for (int p = 0; p < 2; ++p){
                int f4 = (tid & 3) + 4 * p;
                ((float4*)wgs[wgrow])[f4] = ((const float4*)(Wg + (size_t)(k0 + wgrow) * DGZ))[f4];
            }
        }
        __syncthreads();
        #pragma unroll
        for (int kk16 = 0; kk16 < 16; ++kk16){
            int kk = q * 16 + kk16;
            float4 a0 = ((float4*)hsT[kk])[tg*2];
            float4 a1 = ((float4*)hsT[kk])[tg*2+1];
            float4 wv = ((float4*)wgs[kk])[cg];
            float av[8] = {a0.x,a0.y,a0.z,a0.w,a1.x,a1.y,a1.z,a1.w};
            float wj[4] = {wv.x,wv.y,wv.z,wv.w};
            #pragma unroll
            for (int i=0;i<8;++i){
                g_[i][0] += av[i]*wj[0]; g_[i][1] += av[i]*wj[1];
                g_[i][2] += av[i]*wj[2]; g_[i][3] += av[i]*wj[3];
            }
        }
        __syncthreads();
    }
    for (int qq = 0; qq < 4; ++qq){
        if (w == qq){
            #pragma unroll
            for (int i=0;i<8;++i){
                int tok = tg*8+i;
                #pragma unroll
                for (int j=0;j<4;++j){
                    int c = cg*4+j;
                    if (qq == 0) gacc[tok][c] = g_[i][j];
                    else gacc[tok][c] += g_[i][j];
                }
            }
        }
        __syncthreads();
    }
    {
        int tokr = tid >> 2;
        #pragma unroll
        for (int p = 0; p < 2; ++p){
            int f4 = (tid & 3) + 4*p;
            float4 v = ((const float4*)(tok_emb + (size_t)(t0 + tokr) * DSZ))[f4];
            int j = f4 * 4;
            agT[j+0][tokr] = v.x; agT[j+1][tokr] = v.y;
            agT[j+2][tokr] = v.z; agT[j+3][tokr] = v.w;
        }
        int c = tid & 31, tok8 = (tid >> 5) * 8;
        float bgc = bg[c];
        #pragma unroll
        for (int i=0;i<8;++i){
            int tok = tok8 + i;
            agT[32 + c][tok] = gelu_f(gacc[tok][c] + bgc);
        }
        int row = tid >> 2;
        #pragma unroll
        for (int p = 0; p < 4; ++p){
            int f4 = (tid & 3) + 4*p;
            ((float4*)wfs[row])[f4] = ((const float4*)(Wf + (size_t)row * FMZ))[f4];
        }
    }
    __syncthreads();
    {
        int tok = tid & 63, fq = tid >> 6;
        float u_[16];
        #pragma unroll
        for (int i=0;i<16;++i) u_[i]=0.f;
        for (int j = 0; j < 64; ++j){
            float a = agT[j][tok];
            float wv[16];
            *(float4*)&wv[0]  = ((float4*)wfs[j])[fq*4+0];
            *(float4*)&wv[4]  = ((float4*)wfs[j])[fq*4+1];
            *(float4*)&wv[8]  = ((float4*)wfs[j])[fq*4+2];
            *(float4*)&wv[12] = ((float4*)wfs[j])[fq*4+3];
            #pragma unroll
            for (int i=0;i<16;++i) u_[i] += a * wv[i];
        }
        #pragma unroll
        for (int i=0;i<16;++i){
            int f = fq*16+i;
            uT[f][tok] = gelu_f(u_[i] + bfv[f]);
        }
    }
    __syncthreads();
    {
        int tok = tid & 63, e = tid >> 6;
        float lt = 0.f;
        #pragma unroll 8
        for (int f = 0; f < 64; ++f) lt += uT[f][tok] * wrs[f][e];
        logit_s[tok][e] = lt + br[e];
    }
    __syncthreads();
    int my_e = 0, my_pos = 0;
    if (tid < 64){
        int tok = tid;
        float l0 = logit_s[tok][0], l1 = logit_s[tok][1];
        float l2 = logit_s[tok][2], l3 = logit_s[tok][3];
        float mx = fmaxf(fmaxf(l0,l1), fmaxf(l2,l3));
        float p0 = expf(l0-mx), p1 = expf(l1-mx), p2 = expf(l2-mx), p3 = expf(l3-mx);
        float inv = 1.0f / (p0+p1+p2+p3);
        int be = 0; float bp = p0;
        if (p1 > bp){ bp = p1; be = 1; }
        if (p2 > bp){ bp = p2; be = 2; }
        if (p3 > bp){ bp = p3; be = 3; }
        tprob[t0 + tok] = bp * inv;
        prob_s[tok][0] = p0*inv; prob_s[tok][1] = p1*inv;
        prob_s[tok][2] = p2*inv; prob_s[tok][3] = p3*inv;
        my_e = be;
        my_pos = atomicAdd(&lcnt[be], 1);
    }
    __syncthreads();
    if (tid < 4) lbase[tid] = atomicAdd(&cnt[tid], lcnt[tid]);
    __syncthreads();
    if (tid < 64) list[my_e * NTOK + lbase[my_e] + my_pos] = t0 + tid;
    if (tid < 4){
        float s = 0.f;
        for (int t = 0; t < 64; ++t) s += prob_s[t][tid];
        imp_part[blockIdx.x * 4 + tid] = s;
    }
}

// ---------------- kernel 3b: pack h rows into routing order (fp32 -> bf16) ----------------
// Ap[pos] = bf16(h[list[e][g]]),  pos = base[e] + g.  One wave per row.
__global__ __launch_bounds__(256) void k_pack(const float* __restrict__ h,
        const int* __restrict__ list, const int* __restrict__ cnt,
        unsigned short* __restrict__ Ap){
    int wv = threadIdx.x >> 6, l = threadIdx.x & 63;
    int p = blockIdx.x * 4 + wv;
    int b1 = cnt[0], b2 = b1 + cnt[1], b3 = b2 + cnt[2];
    int e, g;
    if (p < b1){ e = 0; g = p; }
    else if (p < b2){ e = 1; g = p - b1; }
    else if (p < b3){ e = 2; g = p - b2; }
    else { e = 3; g = p - b3; }
    int tok = list[e * NTOK + g];
    const float4* src = (const float4*)(h + (size_t)tok * HDIM);
    ushort4* dst = (ushort4*)(Ap + (size_t)p * HDIM);
    #pragma unroll
    for (int i = 0; i < 4; ++i){
        float4 v = src[l + 64 * i];
        ushort4 o; o.x = f2bf(v.x); o.y = f2bf(v.y); o.z = f2bf(v.z); o.w = f2bf(v.w);
        dst[l + 64 * i] = o;
    }
}

// ---------------- grouped expert GEMM: 256x256 tile, 8-phase counted-vmcnt, PACKED A ----------------
// Identical schedule to round 4 (best verified); A rows are now CONTIGUOUS packed positions
// pb+g (no list gather in the K-loop). PH1 writes A1 packed by position (contiguous);
// PH2 epilogue scatters by token (list read once per output row).
template<int KTD, int NT, bool PH1>
__global__ __launch_bounds__(512, 2) void k_gemm256(
    const unsigned short* __restrict__ Abase,
    const unsigned short* __restrict__ Bbase,
    const int* __restrict__ list, const int* __restrict__ cnt_g,
    const float* __restrict__ bias,
    unsigned short* __restrict__ A1out,
    const float* __restrict__ hres,
    const float* __restrict__ tprob,
    float* __restrict__ outp)
{
    constexpr int NKT = KTD / 64;
    constexpr int NKTm1 = NKT - 1;
    __shared__ __align__(16) char lds[131072];
    int e = blockIdx.z;
    int cnt = cnt_g[e];
    int m0 = blockIdx.y * 256;
    if (m0 >= cnt) return;
    int pb = 0;
    for (int i = 0; i < 3; ++i) if (i < e) pb += cnt_g[i];   // packed base of expert e
    int n0 = blockIdx.x * 256;
    int tid = threadIdx.x, w = tid >> 6, l = tid & 63;
    int wr = w >> 2, wc = w & 3;

    // staging mapping: thread -> (row = tid>>2 [+128 on 2nd load], src chunk jsrc)
    int srow = tid >> 2;
    int jsrc = (tid & 3) ^ ((tid >> 3) & 3);
    int g0 = m0 + srow;       if (g0 > cnt-1) g0 = cnt-1;
    int g1 = m0 + 128 + srow; if (g1 > cnt-1) g1 = cnt-1;
    const unsigned short* Asrc0 = Abase + (size_t)(pb + g0) * KTD + jsrc * 8;
    const unsigned short* Asrc1 = Abase + (size_t)(pb + g1) * KTD + jsrc * 8;
    const unsigned short* Bsrc0 = Bbase + ((size_t)e * NT + n0 + srow) * KTD + jsrc * 8;
    const unsigned short* Bsrc1 = Bsrc0 + (size_t)128 * KTD;

    // fragment read offsets (swizzled: chunk = (l>>4) ^ (((l&15)>>1)&3), 2-way banks)
    int lane_off = (l & 15) * 64 + (((l >> 4) ^ (((l & 15) >> 1) & 3)) * 16);
    char* abase = lds + wr * 8192 + lane_off;            // + DOF + KCB + mh*4096 + m*1024
    char* bbase = lds + 65536 + wc * 4096 + lane_off;    // + DOF + KCB + n*1024

#define STAGE_A(KIDX, KC, DOF) do { \
    int kq_ = (KIDX); if (kq_ > NKTm1) kq_ = NKTm1; \
    size_t so_ = (size_t)kq_ * 64 + (KC) * 32; \
    gld_lds16(Asrc0 + so_, lds + (DOF) + (KC) * 16384 + tid * 16); \
    gld_lds16(Asrc1 + so_, lds + (DOF) + (KC) * 16384 + 8192 + tid * 16); } while(0)
#define STAGE_B(KIDX, KC, DOF) do { \
    int kq_ = (KIDX); if (kq_ > NKTm1) kq_ = NKTm1; \
    size_t so_ = (size_t)kq_ * 64 + (KC) * 32; \
    gld_lds16(Bsrc0 + so_, lds + 65536 + (DOF) + (KC) * 16384 + tid * 16); \
    gld_lds16(Bsrc1 + so_, lds + 65536 + (DOF) + (KC) * 16384 + 8192 + tid * 16); } while(0)
#define AFRAG(DOF, KCB, MH, M) (*(const bf16x8*)(abase + (DOF) + (KCB) + (MH) * 4096 + (M) * 1024))
#define BFRAG(DOF, KCB, N)     (*(const bf16x8*)(bbase + (DOF) + (KCB) + (N) * 1024))
#define MM16(MB, A0, A1, A2, A3) do { \
    acc[(MB)+0][0] = __builtin_amdgcn_mfma_f32_16x16x32_bf16(A0, b0, acc[(MB)+0][0], 0,0,0); \
    acc[(MB)+1][0] = __builtin_amdgcn_mfma_f32_16x16x32_bf16(A1, b0, acc[(MB)+1][0], 0,0,0); \
    acc[(MB)+2][0] = __builtin_amdgcn_mfma_f32_16x16x32_bf16(A2, b0, acc[(MB)+2][0], 0,0,0); \
    acc[(MB)+3][0] = __builtin_amdgcn_mfma_f32_16x16x32_bf16(A3, b0, acc[(MB)+3][0], 0,0,0); \
    acc[(MB)+0][1] = __builtin_amdgcn_mfma_f32_16x16x32_bf16(A0, b1, acc[(MB)+0][1], 0,0,0); \
    acc[(MB)+1][1] = __builtin_amdgcn_mfma_f32_16x16x32_bf16(A1, b1, acc[(MB)+1][1], 0,0,0); \
    acc[(MB)+2][1] = __builtin_amdgcn_mfma_f32_16x16x32_bf16(A2, b1, acc[(MB)+2][1], 0,0,0); \
    acc[(MB)+3][1] = __builtin_amdgcn_mfma_f32_16x16x32_bf16(A3, b1, acc[(MB)+3][1], 0,0,0); \
    acc[(MB)+0][2] = __builtin_amdgcn_mfma_f32_16x16x32_bf16(A0, b2, acc[(MB)+0][2], 0,0,0); \
    acc[(MB)+1][2] = __builtin_amdgcn_mfma_f32_16x16x32_bf16(A1, b2, acc[(MB)+1][2], 0,0,0); \
    acc[(MB)+2][2] = __builtin_amdgcn_mfma_f32_16x16x32_bf16(A2, b2, acc[(MB)+2][2], 0,0,0); \
    acc[(MB)+3][2] = __builtin_amdgcn_mfma_f32_16x16x32_bf16(A3, b2, acc[(MB)+3][2], 0,0,0); \
    acc[(MB)+0][3] = __builtin_amdgcn_mfma_f32_16x16x32_bf16(A0, b3, acc[(MB)+0][3], 0,0,0); \
    acc[(MB)+1][3] = __builtin_amdgcn_mfma_f32_16x16x32_bf16(A1, b3, acc[(MB)+1][3], 0,0,0); \
    acc[(MB)+2][3] = __builtin_amdgcn_mfma_f32_16x16x32_bf16(A2, b3, acc[(MB)+2][3], 0,0,0); \
    acc[(MB)+3][3] = __builtin_amdgcn_mfma_f32_16x16x32_bf16(A3, b3, acc[(MB)+3][3], 0,0,0); } while(0)

// PH_AB: loads A mh0 + B fragments of (DOF,KCB), stages one A half-tile, MFMA quadrant 0
#define PH_AB(DOF, KCB, SK, SKC, SDOF) do { \
    bf16x8 a0 = AFRAG(DOF,KCB,0,0), a1 = AFRAG(DOF,KCB,0,1), a2 = AFRAG(DOF,KCB,0,2), a3 = AFRAG(DOF,KCB,0,3); \
    b0 = BFRAG(DOF,KCB,0); b1 = BFRAG(DOF,KCB,1); b2 = BFRAG(DOF,KCB,2); b3 = BFRAG(DOF,KCB,3); \
    STAGE_A(SK, SKC, SDOF); \
    __builtin_amdgcn_s_barrier(); \
    __builtin_amdgcn_s_setprio(1); \
    MM16(0, a0, a1, a2, a3); \
    __builtin_amdgcn_s_setprio(0); \
    asm volatile("s_waitcnt lgkmcnt(0)" ::: "memory"); \
    __builtin_amdgcn_s_barrier(); } while(0)
// PH_A: loads A mh1 fragments (reuses b0..b3), stages one B half-tile, MFMA quadrant 1,
//       counted vmcnt(8) fence (4 half-tiles stay in flight)
#define PH_A(DOF, KCB, SK, SKC, SDOF) do { \
    bf16x8 a0 = AFRAG(DOF,KCB,1,0), a1 = AFRAG(DOF,KCB,1,1), a2 = AFRAG(DOF,KCB,1,2), a3 = AFRAG(DOF,KCB,1,3); \
    STAGE_B(SK, SKC, SDOF); \
    __builtin_amdgcn_s_barrier(); \
    __builtin_amdgcn_s_setprio(1); \
    MM16(4, a0, a1, a2, a3); \
    __builtin_amdgcn_s_setprio(0); \
    asm volatile("s_waitcnt vmcnt(8) lgkmcnt(0)" ::: "memory"); \
    __builtin_amdgcn_s_barrier(); } while(0)

    f32x4 acc[8][4] = {};
    bf16x8 b0, b1, b2, b3;

    // prologue: stage (0,kc0,D0),(0,kc1,D0),(1,kc0,D1); retire (0,kc0) -> 8 in flight
    STAGE_A(0, 0, 0);     STAGE_B(0, 0, 0);
    STAGE_A(0, 1, 0);     STAGE_B(0, 1, 0);
    STAGE_A(1, 0, 32768); STAGE_B(1, 0, 32768);
    asm volatile("s_waitcnt vmcnt(8)" ::: "memory");
    __builtin_amdgcn_s_barrier();

    #pragma unroll 1
    for (int kt = 0; kt < NKT; kt += 2){
        // K-tile kt (buffer 0)
        PH_AB(0,     0,     kt+1, 1, 32768);
        PH_A (0,     0,     kt+1, 1, 32768);
        PH_AB(0,     16384, kt+2, 0, 0);
        PH_A (0,     16384, kt+2, 0, 0);
        // K-tile kt+1 (buffer 32768)
        PH_AB(32768, 0,     kt+2, 1, 0);
        PH_A (32768, 0,     kt+2, 1, 0);
        PH_AB(32768, 16384, kt+3, 0, 32768);
        PH_A (32768, 16384, kt+3, 0, 32768);
    }

    // epilogue: C/D layout col = lane&15 (+16*n), row = (lane>>4)*4 + reg (+16*M)
    float bs[4];
    #pragma unroll
    for (int n = 0; n < 4; ++n)
        bs[n] = bias[e * NT + n0 + wc * 64 + n * 16 + (l & 15)];
    #pragma unroll
    for (int M = 0; M < 8; ++M){
        #pragma unroll
        for (int r = 0; r < 4; ++r){
            int row = wr * 128 + M * 16 + (l >> 4) * 4 + r;
            int g = m0 + row;
            if (g < cnt){
                if (PH1){
                    #pragma unroll
                    for (int n = 0; n < 4; ++n){
                        int col = n0 + wc * 64 + n * 16 + (l & 15);
                        float v = acc[M][n][r] + bs[n];
                        A1out[(size_t)(pb + g) * FFZ + col] = f2bf(gelu_f(v));
                    }
                } else {
                    int tok = list[e * NTOK + g];
                    float sc = 0.5f * tprob[tok];
                    #pragma unroll
                    for (int n = 0; n < 4; ++n){
                        int col = n0 + wc * 64 + n * 16 + (l & 15);
                        float v = acc[M][n][r] + bs[n];
                        size_t o = (size_t)tok * HDIM + col;
                        outp[o] = hres[o] + sc * v;
                    }
                }
            }
        }
    }
#undef STAGE_A
#undef STAGE_B
#undef AFRAG
#undef BFRAG
#undef MM16
#undef PH_AB
#undef PH_A
}

// ---------------- final: lb_loss ----------------
__global__ void k_final(const float* __restrict__ imp_part, const int* __restrict__ cnt,
                        float* __restrict__ outp){
    __shared__ float imp_s[4];
    int tid = threadIdx.x;
    if (tid < 4){
        float s = 0.f;
        for (int b = 0; b < 256; ++b) s += imp_part[b*4 + tid];
        imp_s[tid] = s;
    }
    __syncthreads();
    if (tid == 0){
        float lb = 0.f;
        #pragma unroll
        for (int e = 0; e < 4; ++e) lb += imp_s[e] * (float)cnt[e];
        outp[(size_t)NTOK * HDIM] = (float)NEXP * lb / ((float)NTOK * (float)NTOK + 1e-8f);
    }
}

extern "C" void kernel_launch(void* const* d_in, const int* in_sizes, int n_in,
                              void* d_out, int out_size, void* d_ws, size_t ws_size,
                              hipStream_t stream){
    const float* h       = (const float*)d_in[0];
    const float* tok_emb = (const float*)d_in[1];
    const float* ln_g = (const float*)d_in[3];
    const float* ln_b = (const float*)d_in[4];
    const float* Wg   = (const float*)d_in[5];
    const float* bg   = (const float*)d_in[6];
    const float* Wf   = (const float*)d_in[7];
    const float* bfv  = (const float*)d_in[8];
    const float* Wr   = (const float*)d_in[9];
    const float* br   = (const float*)d_in[10];
    const float* W1   = (const float*)d_in[11];
    const float* b1   = (const float*)d_in[12];
    const float* W2   = (const float*)d_in[13];
    const float* b2   = (const float*)d_in[14];
    float* outp = (float*)d_out;
    char* ws = (char*)d_ws;

    unsigned short* Ap   = (unsigned short*)(ws);               // 33554432 B  packed h rows (bf16)
    unsigned short* W1T  = (unsigned short*)(ws + 33554432);    // 16777216 B  [E][FFZ][HDIM]
    unsigned short* W2T  = (unsigned short*)(ws + 50331648);    // 16777216 B  [E][HDIM][FFZ]
    unsigned short* A1   = (unsigned short*)(ws + 67108864);    // 67108864 B  packed [NTOK][FFZ]
    float* mu_g  = (float*)(ws + 134217728);
    float* rs_g  = (float*)(ws + 134283264);
    float* tprob = (float*)(ws + 134348800);
    int*   list  = (int*)(ws + 134414336);                      // [E][NTOK]
    int*   cnt   = (int*)(ws + 134676480);                      // [E]
    float* imp   = (float*)(ws + 134676736);                    // [256][E]

    hipMemsetAsync(cnt, 0, NEXP * sizeof(int), stream);
    k_stats<<<NTOK/4, 256, 0, stream>>>(h, mu_g, rs_g);
    k_transpose_bf<<<dim3(FFZ/32, HDIM/32, NEXP), dim3(32,8), 0, stream>>>(W1, W1T, HDIM, FFZ);
    k_transpose_bf<<<dim3(HDIM/32, FFZ/32, NEXP), dim3(32,8), 0, stream>>>(W2, W2T, FFZ, HDIM);
    k_route<<<NTOK/64, 256, 0, stream>>>(h, tok_emb, ln_g, ln_b, Wg, bg, Wf, bfv, Wr, br,
                                         mu_g, rs_g, tprob, list, cnt, imp);
    k_pack<<<NTOK/4, 256, 0, stream>>>(h, list, cnt, Ap);
    k_gemm256<HDIM, FFZ, true><<<dim3(FFZ/256, NTOK/256, NEXP), 512, 0, stream>>>(
        Ap, W1T, list, cnt, b1, A1, nullptr, nullptr, nullptr);
    k_gemm256<FFZ, HDIM, false><<<dim3(HDIM/256, NTOK/256, NEXP), 512, 0, stream>>>(
        A1, W2T, list, cnt, b2, nullptr, h, tprob, outp);
    k_final<<<1, 64, 0, stream>>>(imp, cnt, outp);
}